// Round 6
// baseline (905.754 us; speedup 1.0000x reference)
//
#include <hip/hip_runtime.h>

typedef __attribute__((ext_vector_type(8))) short short8;
typedef __attribute__((ext_vector_type(4))) float f32x4;

#define S 4096
#define Dm 512

__device__ __forceinline__ ushort f2bf(float f) {
    union { float f; unsigned u; } v; v.f = f;
    unsigned r = v.u + 0x7FFFu + ((v.u >> 16) & 1u);
    return (ushort)(r >> 16);
}
__device__ __forceinline__ float bf2f(ushort h) {
    union { unsigned u; float f; } v; v.u = ((unsigned)h) << 16; return v.f;
}

__device__ __forceinline__ void gload_lds16(const ushort* g, ushort* l) {
    __builtin_amdgcn_global_load_lds(
        (const __attribute__((address_space(1))) unsigned int*)g,
        (__attribute__((address_space(3))) unsigned int*)l, 16, 0, 0);
}

// ------------- kernel 1: cast fp32 -> bf16 hi/lo splits -------------
__global__ void cast_split(const float* __restrict__ x,
                           const float* __restrict__ Wq, const float* __restrict__ Wk,
                           const float* __restrict__ Wv, const float* __restrict__ Wc,
                           ushort* __restrict__ Xh, ushort* __restrict__ Xl,
                           ushort* __restrict__ Wqh, ushort* __restrict__ Wql,
                           ushort* __restrict__ Wkh, ushort* __restrict__ Wkl,
                           ushort* __restrict__ Wvh, ushort* __restrict__ Wch)
{
    const size_t i8 = ((size_t)blockIdx.x * 256 + threadIdx.x) * 8;
    const size_t NX = 4194304;
    float v[8];
    if (i8 < NX) {
        float4 a = *(const float4*)(x + i8);
        float4 b = *(const float4*)(x + i8 + 4);
        v[0]=a.x; v[1]=a.y; v[2]=a.z; v[3]=a.w; v[4]=b.x; v[5]=b.y; v[6]=b.z; v[7]=b.w;
        short8 h8, l8;
#pragma unroll
        for (int j = 0; j < 8; ++j) {
            ushort hi = f2bf(v[j]);
            h8[j] = (short)hi;
            l8[j] = (short)f2bf(v[j] - bf2f(hi));
        }
        *(short8*)(Xh + i8) = h8;
        *(short8*)(Xl + i8) = l8;
    } else {
        size_t j0 = i8 - NX;
        int wsel = (int)(j0 >> 18);
        size_t off = j0 & 262143;
        const float* src = (wsel == 0) ? Wq : (wsel == 1) ? Wk : (wsel == 2) ? Wv : Wc;
        float4 a = *(const float4*)(src + off);
        float4 b = *(const float4*)(src + off + 4);
        v[0]=a.x; v[1]=a.y; v[2]=a.z; v[3]=a.w; v[4]=b.x; v[5]=b.y; v[6]=b.z; v[7]=b.w;
        short8 h8, l8;
#pragma unroll
        for (int j = 0; j < 8; ++j) {
            ushort hi = f2bf(v[j]);
            h8[j] = (short)hi;
            l8[j] = (short)f2bf(v[j] - bf2f(hi));
        }
        ushort* dh = (wsel == 0) ? Wqh : (wsel == 1) ? Wkh : (wsel == 2) ? Wvh : Wch;
        *(short8*)(dh + off) = h8;
        if (wsel < 2) {
            ushort* dl = wsel ? Wkl : Wql;
            *(short8*)(dl + off) = l8;
        }
    }
}

// ------------- kernel 2: QKV projection (bf16 MFMA; Q,K split, 3-term) ----
__global__ __launch_bounds__(256, 2)
void qkv_gemm(const ushort* __restrict__ Xh, const ushort* __restrict__ Xl,
              const ushort* __restrict__ Wqh, const ushort* __restrict__ Wql,
              const ushort* __restrict__ Wkh, const ushort* __restrict__ Wkl,
              const ushort* __restrict__ Wvh,
              ushort* __restrict__ Qh, ushort* __restrict__ Ql,
              ushort* __restrict__ Kh, ushort* __restrict__ Kl,
              ushort* __restrict__ Vb)
{
    __shared__ ushort xh_sm[128 * 32];
    __shared__ ushort xl_sm[128 * 32];
    const int tid = threadIdx.x;
    const int w = tid >> 6, l = tid & 63, lq = l & 15, lg = l >> 4;
    const int wm = w >> 1, wn = w & 1;
    const int z = blockIdx.z;
    const int m0 = blockIdx.y * 128, n0 = blockIdx.x * 128;
    const ushort* Wh = (z == 0) ? Wqh : (z == 1) ? Wkh : Wvh;
    const ushort* Wl = (z == 0) ? Wql : Wkl;   // unused when z==2

    f32x4 acc[4][4];
#pragma unroll
    for (int i = 0; i < 4; ++i)
#pragma unroll
        for (int j = 0; j < 4; ++j) acc[i][j] = (f32x4){0.f, 0.f, 0.f, 0.f};

    for (int k0 = 0; k0 < 512; k0 += 32) {
        __syncthreads();
#pragma unroll
        for (int it = 0; it < 2; ++it) {
            int L = it * 256 + tid;
            int row = L >> 2, c = L & 3;
            int p = c ^ ((row >> 1) & 3);
            short8 vv = *(const short8*)(Xh + (size_t)(m0 + row) * Dm + k0 + c * 8);
            *(short8*)&xh_sm[row * 32 + p * 8] = vv;
            if (z < 2) {
                short8 v2 = *(const short8*)(Xl + (size_t)(m0 + row) * Dm + k0 + c * 8);
                *(short8*)&xl_sm[row * 32 + p * 8] = v2;
            }
        }
        __syncthreads();
        short8 bh[4], bl[4];
#pragma unroll
        for (int ns = 0; ns < 4; ++ns) {
            bh[ns] = *(const short8*)(Wh + (size_t)(n0 + wn * 64 + ns * 16 + lq) * Dm + k0 + lg * 8);
            if (z < 2)
                bl[ns] = *(const short8*)(Wl + (size_t)(n0 + wn * 64 + ns * 16 + lq) * Dm + k0 + lg * 8);
        }
#pragma unroll
        for (int ms = 0; ms < 4; ++ms) {
            int row = wm * 64 + ms * 16 + lq;
            int p = lg ^ ((row >> 1) & 3);
            short8 ah = *(const short8*)&xh_sm[row * 32 + p * 8];
            if (z < 2) {
                short8 al = *(const short8*)&xl_sm[row * 32 + p * 8];
#pragma unroll
                for (int ns = 0; ns < 4; ++ns) {
                    acc[ms][ns] = __builtin_amdgcn_mfma_f32_16x16x32_bf16(ah, bh[ns], acc[ms][ns], 0, 0, 0);
                    acc[ms][ns] = __builtin_amdgcn_mfma_f32_16x16x32_bf16(ah, bl[ns], acc[ms][ns], 0, 0, 0);
                    acc[ms][ns] = __builtin_amdgcn_mfma_f32_16x16x32_bf16(al, bh[ns], acc[ms][ns], 0, 0, 0);
                }
            } else {
#pragma unroll
                for (int ns = 0; ns < 4; ++ns)
                    acc[ms][ns] = __builtin_amdgcn_mfma_f32_16x16x32_bf16(ah, bh[ns], acc[ms][ns], 0, 0, 0);
            }
        }
    }
    ushort* Yh = (z == 0) ? Qh : (z == 1) ? Kh : Vb;
    ushort* Yl = (z == 0) ? Ql : Kl;
#pragma unroll
    for (int ms = 0; ms < 4; ++ms)
#pragma unroll
        for (int ns = 0; ns < 4; ++ns)
#pragma unroll
            for (int j = 0; j < 4; ++j) {
                int m = m0 + wm * 64 + ms * 16 + lg * 4 + j;
                int n = n0 + wn * 64 + ns * 16 + lq;
                float v = acc[ms][ns][j];
                ushort hi = f2bf(v);
                Yh[(size_t)m * Dm + n] = hi;
                if (z < 2) Yl[(size_t)m * Dm + n] = f2bf(v - bf2f(hi));
            }
}

// ------------- kernel 3: V -> V^T, KT=32-tiled [b][k/32][512 d][32 k] -------
// chunk pre-swizzle on STORE: c' = c ^ (d&3). Staging into LDS is LINEAR;
// the PV read applies the same XOR -> correct data + bank spread.
__global__ void vt_transpose(const ushort* __restrict__ Vb, ushort* __restrict__ VtG)
{
    __shared__ ushort t_sm[64 * 65];
    const int tid = threadIdx.x;
    const int bz = blockIdx.z;
    const int s0 = blockIdx.x * 64;
    const int f0 = blockIdx.y * 64;
#pragma unroll
    for (int it = 0; it < 2; ++it) {
        int r = it * 32 + (tid >> 3);
        int c8 = tid & 7;
        short8 v = *(const short8*)(Vb + (size_t)bz * S * Dm + (size_t)(s0 + r) * Dm + f0 + c8 * 8);
#pragma unroll
        for (int j = 0; j < 8; ++j) t_sm[(c8 * 8 + j) * 65 + r] = (ushort)v[j];
    }
    __syncthreads();
#pragma unroll
    for (int it = 0; it < 2; ++it) {
        int fr = it * 32 + (tid >> 3);
        int sc8 = tid & 7;
        short8 o;
#pragma unroll
        for (int j = 0; j < 8; ++j) o[j] = (short)t_sm[fr * 65 + sc8 * 8 + j];
        int d = f0 + fr;
        int kt = (s0 >> 5) + (sc8 >> 2);
        int c = (sc8 & 3) ^ (fr & 3);
        *(short8*)(VtG + (((size_t)bz * 128 + kt) * 512 + d) * 32 + c * 8) = o;
    }
}

// ------------- kernel 4: fused attention -------------
// 512 threads = 8 waves, 128 q/block; k-range 1024 (ks of 4), KT=32.
// K single-buffer + Vt double-buffer staging, counted vmcnt, 2 barriers/tile.
// Softmax over HEADS lane-local; PV A-frag via wave-private swizzled LDS tile.
__global__ __launch_bounds__(512, 2)
void attn_fused(const ushort* __restrict__ Qhh, const ushort* __restrict__ Qll,
                const ushort* __restrict__ Khh, const ushort* __restrict__ Kll,
                const ushort* __restrict__ VtG,
                ushort* __restrict__ P0, ushort* __restrict__ P1,
                ushort* __restrict__ P2, ushort* __restrict__ P3)
{
    __shared__ __align__(16) ushort Khi[16384];      // [32 k][512 d] chunk-swizzled, 32 KB
    __shared__ __align__(16) ushort Vt[2][16384];    // [buf][512 d][32 k] swizzled, 64 KB
    __shared__ __align__(16) ushort Aw[16384];       // per-wave 4h x 16q x 32k a-tiles, 32 KB
    const int tid = threadIdx.x;
    const int w = tid >> 6, l = tid & 63, lq = l & 15, lg = l >> 4;
    const int bid = blockIdx.x;
    const int qt = bid >> 3, grp = bid & 7;      // grp -> XCD (round-robin dispatch)
    const int bb = grp >> 2, ks = grp & 3;
    const int q_first = qt * 128;
    const int kbeg = ks * 1024;
    const int qsc = q_first + w * 16 + lq;
    const size_t sbase = (size_t)bb * S * Dm;
    const size_t qoff = sbase + (size_t)qsc * Dm;
    const size_t vbase = (size_t)bb * 128 * 16384;
    ushort* __restrict__ Pp = (ks == 0) ? P0 : (ks == 1) ? P1 : (ks == 2) ? P2 : P3;
    const int awb = w * 2048;                    // ushort idx, 4 KB per wave
    const int aswz = (lq & 3) ^ ((lq >> 2) & 3);

    // persistent Q-hi fragments (B-operand: 8 contiguous d per lane)
    short8 qf[8][2];
#pragma unroll
    for (int h = 0; h < 8; ++h)
#pragma unroll
        for (int ds = 0; ds < 2; ++ds)
            qf[h][ds] = *(const short8*)(Qhh + qoff + h * 64 + ds * 32 + lg * 8);

    f32x4 outa[8][4];
#pragma unroll
    for (int h = 0; h < 8; ++h)
#pragma unroll
        for (int d = 0; d < 4; ++d) outa[h][d] = (f32x4){0.f, 0.f, 0.f, 0.f};

#define STAGE_K(KC) do {                                                          \
    const int k0s = kbeg + (KC) * 32;                                             \
    _Pragma("unroll") for (int it = 0; it < 4; ++it) {                            \
        int L = it * 512 + tid; int row = L >> 6; int ch = (L & 63) ^ (row & 7);  \
        gload_lds16(Khh + sbase + (size_t)(k0s + row) * Dm + ch * 8,              \
                    &Khi[L * 8]); }                                               \
} while (0)

// LINEAR source: VtG already carries the chunk pre-swizzle (store side).
#define STAGE_V(KC, BUF) do {                                                     \
    const size_t vsrc = vbase + (size_t)(ks * 32 + (KC)) * 16384;                 \
    _Pragma("unroll") for (int it = 0; it < 4; ++it) {                            \
        int L = it * 512 + tid;                                                   \
        gload_lds16(VtG + vsrc + (size_t)L * 8, &Vt[BUF][L * 8]); }               \
} while (0)

    STAGE_K(0);
    STAGE_V(0, 0);

    unsigned pk[8][4];   // packed bf16 attn weights: [h][sub*2 + {lo,hi} dword]

    for (int kc = 0; kc < 32; ++kc) {
        const int pb = kc & 1;
        const int k0 = kbeg + kc * 32;
        asm volatile("s_waitcnt vmcnt(4)" ::: "memory");   // K(kc) landed (V(kc) pending)
        __builtin_amdgcn_sched_barrier(0);
        __builtin_amdgcn_s_barrier();
        __builtin_amdgcn_sched_barrier(0);

        // ---- scores + softmax per 16-k sub ----
#pragma unroll
        for (int s = 0; s < 2; ++s) {
            f32x4 sc[8];
#pragma unroll
            for (int h = 0; h < 8; ++h) sc[h] = (f32x4){0.f, 0.f, 0.f, 0.f};
            const int krow = s * 16 + lq;
#pragma unroll
            for (int h = 0; h < 8; ++h)
#pragma unroll
                for (int ds = 0; ds < 2; ++ds) {
                    short8 khf = *(const short8*)&Khi[krow * 512 + (((h * 8 + ds * 4 + lg)) ^ (lq & 7)) * 8];
                    sc[h] = __builtin_amdgcn_mfma_f32_16x16x32_bf16(khf, qf[h][ds], sc[h], 0, 0, 0);
                }
            const int kb = k0 + s * 16 + lg * 4;
            // rare 3-term redo near the +-32 rounding boundary (masked region)
            if ((k0 + s * 16 + 15) > q_first) {
                bool flag = false;
#pragma unroll
                for (int j = 0; j < 4; ++j)
                    if ((kb + j) > qsc) {
#pragma unroll
                        for (int h = 0; h < 8; ++h)
                            flag = flag || (fabsf(fabsf(sc[h][j]) - 32.0f) < 0.26f);
                    }
                if (__ballot(flag)) {
#pragma unroll
                    for (int h = 0; h < 8; ++h) {
                        f32x4 t = (f32x4){0.f, 0.f, 0.f, 0.f};
#pragma unroll
                        for (int ds = 0; ds < 2; ++ds) {
                            const int fo = h * 64 + ds * 32 + lg * 8;
                            short8 khf = *(const short8*)&Khi[(s * 16 + lq) * 512 + (((h * 8 + ds * 4 + lg)) ^ (lq & 7)) * 8];
                            short8 qlf = *(const short8*)(Qll + qoff + fo);
                            short8 klf = *(const short8*)(Kll + sbase + (size_t)(k0 + s * 16 + lq) * Dm + fo);
                            t = __builtin_amdgcn_mfma_f32_16x16x32_bf16(klf, qf[h][ds], t, 0, 0, 0);
                            t = __builtin_amdgcn_mfma_f32_16x16x32_bf16(khf, qlf, t, 0, 0, 0);
                            t = __builtin_amdgcn_mfma_f32_16x16x32_bf16(khf, qf[h][ds], t, 0, 0, 0);
                        }
                        sc[h] = t;
                    }
                }
            }
            // softmax over the 8 heads (lane-local, faithful fp32 chain)
#pragma unroll
            for (int j = 0; j < 4; ++j) {
                float xx[8];
                const float madd = ((kb + j) > qsc) ? -1e9f : 0.0f;
#pragma unroll
                for (int h = 0; h < 8; ++h)
                    xx[h] = (sc[h][j] + madd) * 0.125f;
                float mm = fmaxf(fmaxf(fmaxf(xx[0], xx[1]), fmaxf(xx[2], xx[3])),
                                 fmaxf(fmaxf(xx[4], xx[5]), fmaxf(xx[6], xx[7])));
                float e[8]; float den = 0.f;
#pragma unroll
                for (int h = 0; h < 8; ++h) { e[h] = __expf(xx[h] - mm); den += e[h]; }
                float inv = __builtin_amdgcn_rcpf(den);
#pragma unroll
                for (int h = 0; h < 8; ++h) sc[h][j] = e[h] * inv;
            }
            // pack to bf16 (hw RNE pack)
#pragma unroll
            for (int h = 0; h < 8; ++h) {
                unsigned d0, d1;
                asm("v_cvt_pk_bf16_f32 %0, %1, %2" : "=v"(d0) : "v"(sc[h][0]), "v"(sc[h][1]));
                asm("v_cvt_pk_bf16_f32 %0, %1, %2" : "=v"(d1) : "v"(sc[h][2]), "v"(sc[h][3]));
                pk[h][s * 2 + 0] = d0;
                pk[h][s * 2 + 1] = d1;
            }
        }

        asm volatile("s_waitcnt vmcnt(0)" ::: "memory");   // V(kc) landed (all waves' own)
        __builtin_amdgcn_sched_barrier(0);
        __builtin_amdgcn_s_barrier();                      // everyone: scores done + V ready
        __builtin_amdgcn_sched_barrier(0);

        if (kc < 31) STAGE_K(kc + 1);                      // overlaps PV

        // ---- PV in two h-passes through the wave-private A tile ----
#pragma unroll
        for (int p = 0; p < 2; ++p) {
#pragma unroll
            for (int i = 0; i < 4; ++i) {
                int h = p * 4 + i;
#pragma unroll
                for (int s2 = 0; s2 < 2; ++s2) {
                    int u = (s2 * 2 + (lg >> 1)) ^ aswz;
                    uint2 t; t.x = pk[h][s2 * 2]; t.y = pk[h][s2 * 2 + 1];
                    *(uint2*)&Aw[awb + (i * 16 + lq) * 32 + u * 8 + (lg & 1) * 4] = t;
                }
            }
#pragma unroll
            for (int i = 0; i < 4; ++i) {
                int h = p * 4 + i;
                short8 af = *(const short8*)&Aw[awb + (i * 16 + lq) * 32 + ((lg ^ aswz) << 3)];
#pragma unroll
                for (int dsub = 0; dsub < 4; ++dsub) {
                    int drow = h * 64 + dsub * 16 + lq;
                    short8 vf = *(const short8*)&Vt[pb][drow * 32 + ((lg ^ (drow & 3)) << 3)];
                    outa[h][dsub] = __builtin_amdgcn_mfma_f32_16x16x32_bf16(af, vf, outa[h][dsub], 0, 0, 0);
                }
            }
        }

        if (kc < 31) STAGE_V(kc + 1, pb ^ 1);              // buf read last at kc-1: safe
        __builtin_amdgcn_sched_barrier(0);
    }
#undef STAGE_K
#undef STAGE_V

    // epilogue: partial P (this k-split) as bf16
#pragma unroll
    for (int h = 0; h < 8; ++h)
#pragma unroll
        for (int dsub = 0; dsub < 4; ++dsub)
#pragma unroll
            for (int j = 0; j < 4; ++j) {
                int qrow = q_first + w * 16 + lg * 4 + j;
                Pp[sbase + (size_t)qrow * Dm + h * 64 + dsub * 16 + lq] = f2bf(outa[h][dsub][j]);
            }
}

// ------------- kernel 5: out projection + ReLU (sums 4 partials, fp32 out) ----
__global__ __launch_bounds__(256, 2)
void out_gemm(const ushort* __restrict__ P0, const ushort* __restrict__ P1,
              const ushort* __restrict__ P2, const ushort* __restrict__ P3,
              const ushort* __restrict__ Wch, float* __restrict__ Out)
{
    __shared__ ushort a_sm[128 * 32];
    const int tid = threadIdx.x;
    const int w = tid >> 6, l = tid & 63, lq = l & 15, lg = l >> 4;
    const int wm = w >> 1, wn = w & 1;
    const int m0 = blockIdx.y * 128, n0 = blockIdx.x * 128;
    f32x4 acc[4][4];
#pragma unroll
    for (int i = 0; i < 4; ++i)
#pragma unroll
        for (int j = 0; j < 4; ++j) acc[i][j] = (f32x4){0.f, 0.f, 0.f, 0.f};

    for (int k0 = 0; k0 < 512; k0 += 32) {
        __syncthreads();
#pragma unroll
        for (int it = 0; it < 2; ++it) {
            int L = it * 256 + tid;
            int row = L >> 2, c = L & 3;
            int p = c ^ ((row >> 1) & 3);
            size_t idx = (size_t)(m0 + row) * Dm + k0 + c * 8;
            short8 v0 = *(const short8*)(P0 + idx);
            short8 v1 = *(const short8*)(P1 + idx);
            short8 v2 = *(const short8*)(P2 + idx);
            short8 v3 = *(const short8*)(P3 + idx);
            short8 sum;
#pragma unroll
            for (int j = 0; j < 8; ++j) {
                float s = (bf2f((ushort)v0[j]) + bf2f((ushort)v1[j])) +
                          (bf2f((ushort)v2[j]) + bf2f((ushort)v3[j]));
                sum[j] = (short)f2bf(s);
            }
            *(short8*)&a_sm[row * 32 + p * 8] = sum;
        }
        __syncthreads();
        short8 bfrag[4];
#pragma unroll
        for (int ns = 0; ns < 4; ++ns)
            bfrag[ns] = *(const short8*)(Wch + (size_t)(n0 + wn * 64 + ns * 16 + lq) * Dm + k0 + lg * 8);
#pragma unroll
        for (int ms = 0; ms < 4; ++ms) {
            int row = wm * 64 + ms * 16 + lq;
            int p = lg ^ ((row >> 1) & 3);
            short8 afrag = *(const short8*)&a_sm[row * 32 + p * 8];
#pragma unroll
            for (int ns = 0; ns < 4; ++ns)
                acc[ms][ns] = __builtin_amdgcn_mfma_f32_16x16x32_bf16(afrag, bfrag[ns], acc[ms][ns], 0, 0, 0);
        }
    }
#pragma unroll
    for (int ms = 0; ms < 4; ++ms)
#pragma unroll
        for (int ns = 0; ns < 4; ++ns)
#pragma unroll
            for (int j = 0; j < 4; ++j) {
                int m = m0 + wm * 64 + ms * 16 + lg * 4 + j;
                int n = n0 + wn * 64 + ns * 16 + lq;
                Out[(size_t)m * Dm + n] = fmaxf(acc[ms][ns][j], 0.0f);
            }
}

extern "C" void kernel_launch(void* const* d_in, const int* in_sizes, int n_in,
                              void* d_out, int out_size, void* d_ws, size_t ws_size,
                              hipStream_t stream)
{
    const float* x  = (const float*)d_in[0];
    const float* Wq = (const float*)d_in[1];
    const float* Wk = (const float*)d_in[2];
    const float* Wv = (const float*)d_in[3];
    const float* Wc = (const float*)d_in[4];
    float* out = (float*)d_out;

    const size_t SZ = 4194304;   // 2*4096*512
    const size_t WZ = 262144;    // 512*512
    ushort* ws16 = (ushort*)d_ws;
    ushort* Xh  = ws16;           // reused as P0 after qkv
    ushort* Xl  = Xh + SZ;        // reused as P1 after qkv
    ushort* Wqh = Xl + SZ;
    ushort* Wql = Wqh + WZ;
    ushort* Wkh = Wql + WZ;
    ushort* Wkl = Wkh + WZ;
    ushort* Wvh = Wkl + WZ;
    ushort* Wch = Wvh + WZ;
    ushort* Qh  = Wch + WZ;
    ushort* Ql  = Qh + SZ;
    ushort* Kh  = Ql + SZ;
    ushort* Kl  = Kh + SZ;
    ushort* Vb  = Kl + SZ;        // reused as P2 after vt_transpose
    ushort* Vt  = Vb + SZ;
    ushort* P3  = Vt + SZ;        // total ~75.5 MB

    cast_split<<<2560, 256, 0, stream>>>(x, Wq, Wk, Wv, Wc, Xh, Xl,
                                         Wqh, Wql, Wkh, Wkl, Wvh, Wch);
    qkv_gemm<<<dim3(4, 64, 3), 256, 0, stream>>>(Xh, Xl, Wqh, Wql, Wkh, Wkl, Wvh,
                                                 Qh, Ql, Kh, Kl, Vb);
    vt_transpose<<<dim3(64, 8, 2), 256, 0, stream>>>(Vb, Vt);
    attn_fused<<<dim3(256), 512, 0, stream>>>(Qh, Ql, Kh, Kl, Vt,
                                              Xh, Xl, Vb, P3);
    out_gemm<<<dim3(4, 64), 256, 0, stream>>>(Xh, Xl, Vb, P3, Wch, out);
}

// Round 7
// 898.193 us; speedup vs baseline: 1.0084x; 1.0084x over previous
//
#include <hip/hip_runtime.h>

typedef __attribute__((ext_vector_type(8))) short short8;
typedef __attribute__((ext_vector_type(4))) float f32x4;

#define S 4096
#define Dm 512

__device__ __forceinline__ ushort f2bf(float f) {
    union { float f; unsigned u; } v; v.f = f;
    unsigned r = v.u + 0x7FFFu + ((v.u >> 16) & 1u);
    return (ushort)(r >> 16);
}
__device__ __forceinline__ float bf2f(ushort h) {
    union { unsigned u; float f; } v; v.u = ((unsigned)h) << 16; return v.f;
}

__device__ __forceinline__ void gload_lds16(const ushort* g, ushort* l) {
    __builtin_amdgcn_global_load_lds(
        (const __attribute__((address_space(1))) unsigned int*)g,
        (__attribute__((address_space(3))) unsigned int*)l, 16, 0, 0);
}

// ------------- kernel 1: cast fp32 -> bf16 hi/lo splits -------------
__global__ void cast_split(const float* __restrict__ x,
                           const float* __restrict__ Wq, const float* __restrict__ Wk,
                           const float* __restrict__ Wv, const float* __restrict__ Wc,
                           ushort* __restrict__ Xh, ushort* __restrict__ Xl,
                           ushort* __restrict__ Wqh, ushort* __restrict__ Wql,
                           ushort* __restrict__ Wkh, ushort* __restrict__ Wkl,
                           ushort* __restrict__ Wvh, ushort* __restrict__ Wch)
{
    const size_t i8 = ((size_t)blockIdx.x * 256 + threadIdx.x) * 8;
    const size_t NX = 4194304;
    float v[8];
    if (i8 < NX) {
        float4 a = *(const float4*)(x + i8);
        float4 b = *(const float4*)(x + i8 + 4);
        v[0]=a.x; v[1]=a.y; v[2]=a.z; v[3]=a.w; v[4]=b.x; v[5]=b.y; v[6]=b.z; v[7]=b.w;
        short8 h8, l8;
#pragma unroll
        for (int j = 0; j < 8; ++j) {
            ushort hi = f2bf(v[j]);
            h8[j] = (short)hi;
            l8[j] = (short)f2bf(v[j] - bf2f(hi));
        }
        *(short8*)(Xh + i8) = h8;
        *(short8*)(Xl + i8) = l8;
    } else {
        size_t j0 = i8 - NX;
        int wsel = (int)(j0 >> 18);
        size_t off = j0 & 262143;
        const float* src = (wsel == 0) ? Wq : (wsel == 1) ? Wk : (wsel == 2) ? Wv : Wc;
        float4 a = *(const float4*)(src + off);
        float4 b = *(const float4*)(src + off + 4);
        v[0]=a.x; v[1]=a.y; v[2]=a.z; v[3]=a.w; v[4]=b.x; v[5]=b.y; v[6]=b.z; v[7]=b.w;
        short8 h8, l8;
#pragma unroll
        for (int j = 0; j < 8; ++j) {
            ushort hi = f2bf(v[j]);
            h8[j] = (short)hi;
            l8[j] = (short)f2bf(v[j] - bf2f(hi));
        }
        ushort* dh = (wsel == 0) ? Wqh : (wsel == 1) ? Wkh : (wsel == 2) ? Wvh : Wch;
        *(short8*)(dh + off) = h8;
        if (wsel < 2) {
            ushort* dl = wsel ? Wkl : Wql;
            *(short8*)(dl + off) = l8;
        }
    }
}

// ------------- kernel 2: QKV projection (bf16 MFMA; Q,K split, 3-term) ----
__global__ __launch_bounds__(256, 2)
void qkv_gemm(const ushort* __restrict__ Xh, const ushort* __restrict__ Xl,
              const ushort* __restrict__ Wqh, const ushort* __restrict__ Wql,
              const ushort* __restrict__ Wkh, const ushort* __restrict__ Wkl,
              const ushort* __restrict__ Wvh,
              ushort* __restrict__ Qh, ushort* __restrict__ Ql,
              ushort* __restrict__ Kh, ushort* __restrict__ Kl,
              ushort* __restrict__ Vb)
{
    __shared__ ushort xh_sm[128 * 32];
    __shared__ ushort xl_sm[128 * 32];
    const int tid = threadIdx.x;
    const int w = tid >> 6, l = tid & 63, lq = l & 15, lg = l >> 4;
    const int wm = w >> 1, wn = w & 1;
    const int z = blockIdx.z;
    const int m0 = blockIdx.y * 128, n0 = blockIdx.x * 128;
    const ushort* Wh = (z == 0) ? Wqh : (z == 1) ? Wkh : Wvh;
    const ushort* Wl = (z == 0) ? Wql : Wkl;   // unused when z==2

    f32x4 acc[4][4];
#pragma unroll
    for (int i = 0; i < 4; ++i)
#pragma unroll
        for (int j = 0; j < 4; ++j) acc[i][j] = (f32x4){0.f, 0.f, 0.f, 0.f};

    for (int k0 = 0; k0 < 512; k0 += 32) {
        __syncthreads();
#pragma unroll
        for (int it = 0; it < 2; ++it) {
            int L = it * 256 + tid;
            int row = L >> 2, c = L & 3;
            int p = c ^ ((row >> 1) & 3);
            short8 vv = *(const short8*)(Xh + (size_t)(m0 + row) * Dm + k0 + c * 8);
            *(short8*)&xh_sm[row * 32 + p * 8] = vv;
            if (z < 2) {
                short8 v2 = *(const short8*)(Xl + (size_t)(m0 + row) * Dm + k0 + c * 8);
                *(short8*)&xl_sm[row * 32 + p * 8] = v2;
            }
        }
        __syncthreads();
        short8 bh[4], bl[4];
#pragma unroll
        for (int ns = 0; ns < 4; ++ns) {
            bh[ns] = *(const short8*)(Wh + (size_t)(n0 + wn * 64 + ns * 16 + lq) * Dm + k0 + lg * 8);
            if (z < 2)
                bl[ns] = *(const short8*)(Wl + (size_t)(n0 + wn * 64 + ns * 16 + lq) * Dm + k0 + lg * 8);
        }
#pragma unroll
        for (int ms = 0; ms < 4; ++ms) {
            int row = wm * 64 + ms * 16 + lq;
            int p = lg ^ ((row >> 1) & 3);
            short8 ah = *(const short8*)&xh_sm[row * 32 + p * 8];
            if (z < 2) {
                short8 al = *(const short8*)&xl_sm[row * 32 + p * 8];
#pragma unroll
                for (int ns = 0; ns < 4; ++ns) {
                    acc[ms][ns] = __builtin_amdgcn_mfma_f32_16x16x32_bf16(ah, bh[ns], acc[ms][ns], 0, 0, 0);
                    acc[ms][ns] = __builtin_amdgcn_mfma_f32_16x16x32_bf16(ah, bl[ns], acc[ms][ns], 0, 0, 0);
                    acc[ms][ns] = __builtin_amdgcn_mfma_f32_16x16x32_bf16(al, bh[ns], acc[ms][ns], 0, 0, 0);
                }
            } else {
#pragma unroll
                for (int ns = 0; ns < 4; ++ns)
                    acc[ms][ns] = __builtin_amdgcn_mfma_f32_16x16x32_bf16(ah, bh[ns], acc[ms][ns], 0, 0, 0);
            }
        }
    }
    ushort* Yh = (z == 0) ? Qh : (z == 1) ? Kh : Vb;
    ushort* Yl = (z == 0) ? Ql : Kl;
#pragma unroll
    for (int ms = 0; ms < 4; ++ms)
#pragma unroll
        for (int ns = 0; ns < 4; ++ns)
#pragma unroll
            for (int j = 0; j < 4; ++j) {
                int m = m0 + wm * 64 + ms * 16 + lg * 4 + j;
                int n = n0 + wn * 64 + ns * 16 + lq;
                float v = acc[ms][ns][j];
                ushort hi = f2bf(v);
                Yh[(size_t)m * Dm + n] = hi;
                if (z < 2) Yl[(size_t)m * Dm + n] = f2bf(v - bf2f(hi));
            }
}

// ------------- kernel 3: V -> V^T, KT=32-tiled [b][k/32][512 d][32 k] -------
// chunk pre-swizzle on STORE: c' = c ^ (d&3). Staging into LDS is LINEAR;
// the PV read applies the same XOR -> correct data + bank spread.
__global__ void vt_transpose(const ushort* __restrict__ Vb, ushort* __restrict__ VtG)
{
    __shared__ ushort t_sm[64 * 65];
    const int tid = threadIdx.x;
    const int bz = blockIdx.z;
    const int s0 = blockIdx.x * 64;
    const int f0 = blockIdx.y * 64;
#pragma unroll
    for (int it = 0; it < 2; ++it) {
        int r = it * 32 + (tid >> 3);
        int c8 = tid & 7;
        short8 v = *(const short8*)(Vb + (size_t)bz * S * Dm + (size_t)(s0 + r) * Dm + f0 + c8 * 8);
#pragma unroll
        for (int j = 0; j < 8; ++j) t_sm[(c8 * 8 + j) * 65 + r] = (ushort)v[j];
    }
    __syncthreads();
#pragma unroll
    for (int it = 0; it < 2; ++it) {
        int fr = it * 32 + (tid >> 3);
        int sc8 = tid & 7;
        short8 o;
#pragma unroll
        for (int j = 0; j < 8; ++j) o[j] = (short)t_sm[fr * 65 + sc8 * 8 + j];
        int d = f0 + fr;
        int kt = (s0 >> 5) + (sc8 >> 2);
        int c = (sc8 & 3) ^ (fr & 3);
        *(short8*)(VtG + (((size_t)bz * 128 + kt) * 512 + d) * 32 + c * 8) = o;
    }
}

// ------------- kernel 4: fused attention -------------
// 512 threads = 8 waves, 128 q/block; k-range 1024 (ks of 4), KT=32.
// K single-buffer + Vt double-buffer staging, counted vmcnt, 2 barriers/tile.
// Softmax over HEADS lane-local; PV A-frag via wave-private swizzled LDS tile.
// launch_bounds(512,1): LDS (128KB) caps at 1 block/CU anyway; demanding 2
// capped VGPRs at 128 and forced scratch spills (r6: 1.03 GB WRITE_SIZE).
__global__ __launch_bounds__(512, 1)
void attn_fused(const ushort* __restrict__ Qhh, const ushort* __restrict__ Qll,
                const ushort* __restrict__ Khh, const ushort* __restrict__ Kll,
                const ushort* __restrict__ VtG,
                ushort* __restrict__ P0, ushort* __restrict__ P1,
                ushort* __restrict__ P2, ushort* __restrict__ P3)
{
    __shared__ __align__(16) ushort Khi[16384];      // [32 k][512 d] chunk-swizzled, 32 KB
    __shared__ __align__(16) ushort Vt[2][16384];    // [buf][512 d][32 k] swizzled, 64 KB
    __shared__ __align__(16) ushort Aw[16384];       // per-wave 4h x 16q x 32k a-tiles, 32 KB
    const int tid = threadIdx.x;
    const int w = tid >> 6, l = tid & 63, lq = l & 15, lg = l >> 4;
    const int bid = blockIdx.x;
    const int qt = bid >> 3, grp = bid & 7;      // grp -> XCD (round-robin dispatch)
    const int bb = grp >> 2, ks = grp & 3;
    const int q_first = qt * 128;
    const int kbeg = ks * 1024;
    const int qsc = q_first + w * 16 + lq;
    const size_t sbase = (size_t)bb * S * Dm;
    const size_t qoff = sbase + (size_t)qsc * Dm;
    const size_t vbase = (size_t)bb * 128 * 16384;
    ushort* __restrict__ Pp = (ks == 0) ? P0 : (ks == 1) ? P1 : (ks == 2) ? P2 : P3;
    const int awb = w * 2048;                    // ushort idx, 4 KB per wave
    const int aswz = (lq & 3) ^ ((lq >> 2) & 3);

    // persistent Q-hi fragments (B-operand: 8 contiguous d per lane)
    short8 qf[8][2];
#pragma unroll
    for (int h = 0; h < 8; ++h)
#pragma unroll
        for (int ds = 0; ds < 2; ++ds)
            qf[h][ds] = *(const short8*)(Qhh + qoff + h * 64 + ds * 32 + lg * 8);

    f32x4 outa[8][4];
#pragma unroll
    for (int h = 0; h < 8; ++h)
#pragma unroll
        for (int d = 0; d < 4; ++d) outa[h][d] = (f32x4){0.f, 0.f, 0.f, 0.f};

#define STAGE_K(KC) do {                                                          \
    const int k0s = kbeg + (KC) * 32;                                             \
    _Pragma("unroll") for (int it = 0; it < 4; ++it) {                            \
        int L = it * 512 + tid; int row = L >> 6; int ch = (L & 63) ^ (row & 7);  \
        gload_lds16(Khh + sbase + (size_t)(k0s + row) * Dm + ch * 8,              \
                    &Khi[L * 8]); }                                               \
} while (0)

// LINEAR source: VtG already carries the chunk pre-swizzle (store side).
#define STAGE_V(KC, BUF) do {                                                     \
    const size_t vsrc = vbase + (size_t)(ks * 32 + (KC)) * 16384;                 \
    _Pragma("unroll") for (int it = 0; it < 4; ++it) {                            \
        int L = it * 512 + tid;                                                   \
        gload_lds16(VtG + vsrc + (size_t)L * 8, &Vt[BUF][L * 8]); }               \
} while (0)

    STAGE_K(0);
    STAGE_V(0, 0);

    unsigned pk[8][4];   // packed bf16 attn weights: [h][sub*2 + {lo,hi} dword]

    for (int kc = 0; kc < 32; ++kc) {
        const int pb = kc & 1;
        const int k0 = kbeg + kc * 32;
        asm volatile("s_waitcnt vmcnt(4)" ::: "memory");   // K(kc) landed (V(kc) pending)
        __builtin_amdgcn_sched_barrier(0);
        __builtin_amdgcn_s_barrier();
        __builtin_amdgcn_sched_barrier(0);

        // ---- scores + softmax per 16-k sub ----
#pragma unroll
        for (int s = 0; s < 2; ++s) {
            f32x4 sc[8];
#pragma unroll
            for (int h = 0; h < 8; ++h) sc[h] = (f32x4){0.f, 0.f, 0.f, 0.f};
            const int krow = s * 16 + lq;
#pragma unroll
            for (int h = 0; h < 8; ++h)
#pragma unroll
                for (int ds = 0; ds < 2; ++ds) {
                    short8 khf = *(const short8*)&Khi[krow * 512 + (((h * 8 + ds * 4 + lg)) ^ (lq & 7)) * 8];
                    sc[h] = __builtin_amdgcn_mfma_f32_16x16x32_bf16(khf, qf[h][ds], sc[h], 0, 0, 0);
                }
            const int kb = k0 + s * 16 + lg * 4;
            // rare 3-term redo near the +-32 rounding boundary (masked region)
            if ((k0 + s * 16 + 15) > q_first) {
                bool flag = false;
#pragma unroll
                for (int j = 0; j < 4; ++j)
                    if ((kb + j) > qsc) {
#pragma unroll
                        for (int h = 0; h < 8; ++h)
                            flag = flag || (fabsf(fabsf(sc[h][j]) - 32.0f) < 0.26f);
                    }
                if (__ballot(flag)) {
#pragma unroll
                    for (int h = 0; h < 8; ++h) {
                        f32x4 t = (f32x4){0.f, 0.f, 0.f, 0.f};
#pragma unroll
                        for (int ds = 0; ds < 2; ++ds) {
                            const int fo = h * 64 + ds * 32 + lg * 8;
                            short8 khf = *(const short8*)&Khi[(s * 16 + lq) * 512 + (((h * 8 + ds * 4 + lg)) ^ (lq & 7)) * 8];
                            short8 qlf = *(const short8*)(Qll + qoff + fo);
                            short8 klf = *(const short8*)(Kll + sbase + (size_t)(k0 + s * 16 + lq) * Dm + fo);
                            t = __builtin_amdgcn_mfma_f32_16x16x32_bf16(klf, qf[h][ds], t, 0, 0, 0);
                            t = __builtin_amdgcn_mfma_f32_16x16x32_bf16(khf, qlf, t, 0, 0, 0);
                            t = __builtin_amdgcn_mfma_f32_16x16x32_bf16(khf, qf[h][ds], t, 0, 0, 0);
                        }
                        sc[h] = t;
                    }
                }
            }
            // softmax over the 8 heads (lane-local, faithful fp32 chain)
#pragma unroll
            for (int j = 0; j < 4; ++j) {
                float xx[8];
                const float madd = ((kb + j) > qsc) ? -1e9f : 0.0f;
#pragma unroll
                for (int h = 0; h < 8; ++h)
                    xx[h] = (sc[h][j] + madd) * 0.125f;
                float mm = fmaxf(fmaxf(fmaxf(xx[0], xx[1]), fmaxf(xx[2], xx[3])),
                                 fmaxf(fmaxf(xx[4], xx[5]), fmaxf(xx[6], xx[7])));
                float e[8]; float den = 0.f;
#pragma unroll
                for (int h = 0; h < 8; ++h) { e[h] = __expf(xx[h] - mm); den += e[h]; }
                float inv = __builtin_amdgcn_rcpf(den);
#pragma unroll
                for (int h = 0; h < 8; ++h) sc[h][j] = e[h] * inv;
            }
            // pack to bf16 (hw RNE pack)
#pragma unroll
            for (int h = 0; h < 8; ++h) {
                unsigned d0, d1;
                asm("v_cvt_pk_bf16_f32 %0, %1, %2" : "=v"(d0) : "v"(sc[h][0]), "v"(sc[h][1]));
                asm("v_cvt_pk_bf16_f32 %0, %1, %2" : "=v"(d1) : "v"(sc[h][2]), "v"(sc[h][3]));
                pk[h][s * 2 + 0] = d0;
                pk[h][s * 2 + 1] = d1;
            }
        }

        asm volatile("s_waitcnt vmcnt(0)" ::: "memory");   // V(kc) landed (all waves' own)
        __builtin_amdgcn_sched_barrier(0);
        __builtin_amdgcn_s_barrier();                      // everyone: scores done + V ready
        __builtin_amdgcn_sched_barrier(0);

        if (kc < 31) STAGE_K(kc + 1);                      // overlaps PV

        // ---- PV in two h-passes through the wave-private A tile ----
#pragma unroll
        for (int p = 0; p < 2; ++p) {
#pragma unroll
            for (int i = 0; i < 4; ++i) {
                int h = p * 4 + i;
#pragma unroll
                for (int s2 = 0; s2 < 2; ++s2) {
                    int u = (s2 * 2 + (lg >> 1)) ^ aswz;
                    uint2 t; t.x = pk[h][s2 * 2]; t.y = pk[h][s2 * 2 + 1];
                    *(uint2*)&Aw[awb + (i * 16 + lq) * 32 + u * 8 + (lg & 1) * 4] = t;
                }
            }
#pragma unroll
            for (int i = 0; i < 4; ++i) {
                int h = p * 4 + i;
                short8 af = *(const short8*)&Aw[awb + (i * 16 + lq) * 32 + ((lg ^ aswz) << 3)];
#pragma unroll
                for (int dsub = 0; dsub < 4; ++dsub) {
                    int drow = h * 64 + dsub * 16 + lq;
                    short8 vf = *(const short8*)&Vt[pb][drow * 32 + ((lg ^ (drow & 3)) << 3)];
                    outa[h][dsub] = __builtin_amdgcn_mfma_f32_16x16x32_bf16(af, vf, outa[h][dsub], 0, 0, 0);
                }
            }
        }

        if (kc < 31) STAGE_V(kc + 1, pb ^ 1);              // buf read last at kc-1: safe
        __builtin_amdgcn_sched_barrier(0);
    }
#undef STAGE_K
#undef STAGE_V

    // epilogue: partial P (this k-split) as bf16
#pragma unroll
    for (int h = 0; h < 8; ++h)
#pragma unroll
        for (int dsub = 0; dsub < 4; ++dsub)
#pragma unroll
            for (int j = 0; j < 4; ++j) {
                int qrow = q_first + w * 16 + lg * 4 + j;
                Pp[sbase + (size_t)qrow * Dm + h * 64 + dsub * 16 + lq] = f2bf(outa[h][dsub][j]);
            }
}

// ------------- kernel 5: out projection + ReLU (sums 4 partials, fp32 out) ----
__global__ __launch_bounds__(256, 2)
void out_gemm(const ushort* __restrict__ P0, const ushort* __restrict__ P1,
              const ushort* __restrict__ P2, const ushort* __restrict__ P3,
              const ushort* __restrict__ Wch, float* __restrict__ Out)
{
    __shared__ ushort a_sm[128 * 32];
    const int tid = threadIdx.x;
    const int w = tid >> 6, l = tid & 63, lq = l & 15, lg = l >> 4;
    const int wm = w >> 1, wn = w & 1;
    const int m0 = blockIdx.y * 128, n0 = blockIdx.x * 128;
    f32x4 acc[4][4];
#pragma unroll
    for (int i = 0; i < 4; ++i)
#pragma unroll
        for (int j = 0; j < 4; ++j) acc[i][j] = (f32x4){0.f, 0.f, 0.f, 0.f};

    for (int k0 = 0; k0 < 512; k0 += 32) {
        __syncthreads();
#pragma unroll
        for (int it = 0; it < 2; ++it) {
            int L = it * 256 + tid;
            int row = L >> 2, c = L & 3;
            int p = c ^ ((row >> 1) & 3);
            size_t idx = (size_t)(m0 + row) * Dm + k0 + c * 8;
            short8 v0 = *(const short8*)(P0 + idx);
            short8 v1 = *(const short8*)(P1 + idx);
            short8 v2 = *(const short8*)(P2 + idx);
            short8 v3 = *(const short8*)(P3 + idx);
            short8 sum;
#pragma unroll
            for (int j = 0; j < 8; ++j) {
                float s = (bf2f((ushort)v0[j]) + bf2f((ushort)v1[j])) +
                          (bf2f((ushort)v2[j]) + bf2f((ushort)v3[j]));
                sum[j] = (short)f2bf(s);
            }
            *(short8*)&a_sm[row * 32 + p * 8] = sum;
        }
        __syncthreads();
        short8 bfrag[4];
#pragma unroll
        for (int ns = 0; ns < 4; ++ns)
            bfrag[ns] = *(const short8*)(Wch + (size_t)(n0 + wn * 64 + ns * 16 + lq) * Dm + k0 + lg * 8);
#pragma unroll
        for (int ms = 0; ms < 4; ++ms) {
            int row = wm * 64 + ms * 16 + lq;
            int p = lg ^ ((row >> 1) & 3);
            short8 afrag = *(const short8*)&a_sm[row * 32 + p * 8];
#pragma unroll
            for (int ns = 0; ns < 4; ++ns)
                acc[ms][ns] = __builtin_amdgcn_mfma_f32_16x16x32_bf16(afrag, bfrag[ns], acc[ms][ns], 0, 0, 0);
        }
    }
#pragma unroll
    for (int ms = 0; ms < 4; ++ms)
#pragma unroll
        for (int ns = 0; ns < 4; ++ns)
#pragma unroll
            for (int j = 0; j < 4; ++j) {
                int m = m0 + wm * 64 + ms * 16 + lg * 4 + j;
                int n = n0 + wn * 64 + ns * 16 + lq;
                Out[(size_t)m * Dm + n] = fmaxf(acc[ms][ns][j], 0.0f);
            }
}

extern "C" void kernel_launch(void* const* d_in, const int* in_sizes, int n_in,
                              void* d_out, int out_size, void* d_ws, size_t ws_size,
                              hipStream_t stream)
{
    const float* x  = (const float*)d_in[0];
    const float* Wq = (const float*)d_in[1];
    const float* Wk = (const float*)d_in[2];
    const float* Wv = (const float*)d_in[3];
    const float* Wc = (const float*)d_in[4];
    float* out = (float*)d_out;

    const size_t SZ = 4194304;   // 2*4096*512
    const size_t WZ = 262144;    // 512*512
    ushort* ws16 = (ushort*)d_ws;
    ushort* Xh  = ws16;           // reused as P0 after qkv
    ushort* Xl  = Xh + SZ;        // reused as P1 after qkv
    ushort* Wqh = Xl + SZ;
    ushort* Wql = Wqh + WZ;
    ushort* Wkh = Wql + WZ;
    ushort* Wkl = Wkh + WZ;
    ushort* Wvh = Wkl + WZ;
    ushort* Wch = Wvh + WZ;
    ushort* Qh  = Wch + WZ;
    ushort* Ql  = Qh + SZ;
    ushort* Kh  = Ql + SZ;
    ushort* Kl  = Kh + SZ;
    ushort* Vb  = Kl + SZ;        // reused as P2 after vt_transpose
    ushort* Vt  = Vb + SZ;
    ushort* P3  = Vt + SZ;        // total ~75.5 MB

    cast_split<<<2560, 256, 0, stream>>>(x, Wq, Wk, Wv, Wc, Xh, Xl,
                                         Wqh, Wql, Wkh, Wkl, Wvh, Wch);
    qkv_gemm<<<dim3(4, 64, 3), 256, 0, stream>>>(Xh, Xl, Wqh, Wql, Wkh, Wkl, Wvh,
                                                 Qh, Ql, Kh, Kl, Vb);
    vt_transpose<<<dim3(64, 8, 2), 256, 0, stream>>>(Vb, Vt);
    attn_fused<<<dim3(256), 512, 0, stream>>>(Qh, Ql, Kh, Kl, Vt,
                                              Xh, Xl, Vb, P3);
    out_gemm<<<dim3(4, 64), 256, 0, stream>>>(Xh, Xl, Vb, P3, Wch, out);
}